// Round 6
// baseline (1329.900 us; speedup 1.0000x reference)
//
#include <hip/hip_runtime.h>

#define NN 100000
#define NE 1600000
#define H  128
#define SCAN_CHUNK 512
#define NB_SCAN ((NN + SCAN_CHUNK - 1) / SCAN_CHUNK)   // 196

typedef float f2 __attribute__((ext_vector_type(2)));

__device__ __forceinline__ f2 pkfma(f2 a, f2 b, f2 c) {
    return __builtin_elementwise_fma(a, b, c);
}

// ---------------- zero int array ----------------
__global__ void zero_int(int* __restrict__ p, int n) {
    int i = blockIdx.x * blockDim.x + threadIdx.x;
    if (i < n) p[i] = 0;
}

// ---------------- histogram of dst ----------------
__global__ void hist_kernel(const int* __restrict__ ei, int* __restrict__ deg) {
    int e = blockIdx.x * 256 + threadIdx.x;
    if (e < NE) atomicAdd(&deg[ei[NE + e]], 1);
}

// ---------------- per-chunk exclusive scan ----------------
__global__ __launch_bounds__(SCAN_CHUNK) void scan_block(const int* __restrict__ deg,
                                                         int* __restrict__ off,
                                                         int* __restrict__ sums, int n) {
    __shared__ int buf[SCAN_CHUNK];
    int base = blockIdx.x * SCAN_CHUNK;
    int t = threadIdx.x;
    int v = (base + t < n) ? deg[base + t] : 0;
    buf[t] = v;
    __syncthreads();
    for (int s = 1; s < SCAN_CHUNK; s <<= 1) {
        int add = (t >= s) ? buf[t - s] : 0;
        __syncthreads();
        buf[t] += add;
        __syncthreads();
    }
    if (base + t < n) off[base + t] = buf[t] - v;
    if (t == SCAN_CHUNK - 1) sums[blockIdx.x] = buf[t];
}

__global__ __launch_bounds__(256) void scan_sums(int* __restrict__ sums, int nb) {
    __shared__ int buf[256];
    int t = threadIdx.x;
    int v = (t < nb) ? sums[t] : 0;
    buf[t] = v;
    __syncthreads();
    for (int s = 1; s < 256; s <<= 1) {
        int add = (t >= s) ? buf[t - s] : 0;
        __syncthreads();
        buf[t] += add;
        __syncthreads();
    }
    if (t < nb) sums[t] = buf[t] - v;
}

__global__ void scan_add(int* __restrict__ off, const int* __restrict__ sums,
                         int* __restrict__ cur, int n) {
    int i = blockIdx.x * 256 + threadIdx.x;
    if (i < n) {
        int v = off[i] + sums[i >> 9];
        off[i] = v;
        cur[i] = v;
    }
}

// ---------------- fill CSR with packed (src, weight) ----------------
__global__ void fill_kernel(const int* __restrict__ ei, const float* __restrict__ ew,
                            int* __restrict__ cur, int2* __restrict__ csr) {
    int e = blockIdx.x * 256 + threadIdx.x;
    if (e >= NE) return;
    int d = ei[NE + e];
    int pos = atomicAdd(&cur[d], 1);
    csr[pos] = make_int2(ei[e], __float_as_int(ew[e]));
}

// ---- merged precompute: blocks 0..127 -> W3 rows; block 128 -> b4 ----
__global__ __launch_bounds__(128) void precompute_all(const float* __restrict__ W_node,
                                                      const float* __restrict__ W_cat2,
                                                      const float* __restrict__ b_edge,
                                                      const float* __restrict__ W_cat1,
                                                      const float* __restrict__ b_node,
                                                      const float* __restrict__ b_cat1,
                                                      const float* __restrict__ b_cat2,
                                                      float* __restrict__ W3,
                                                      float* __restrict__ b4) {
    int c = threadIdx.x;
    if (blockIdx.x < H) {
        int k = blockIdx.x;
        __shared__ float wrow[H];
        wrow[c] = W_node[k * H + c];
        __syncthreads();
        float acc = wrow[c];   // identity part of (I + W_cat2)
        #pragma unroll 8
        for (int j = 0; j < H; ++j)
            acc += wrow[j] * W_cat2[j * H + c];
        W3[k * H + c] = acc;
    } else {
        __shared__ float be[H], bn[H];
        be[c] = b_edge[c];
        bn[c] = b_node[c];
        __syncthreads();
        float acc = be[c] + bn[c] + b_cat1[c] + b_cat2[c];
        for (int j = 0; j < H; ++j)
            acc += be[j] * W_cat1[j * H + c] + bn[j] * W_cat2[j * H + c];
        b4[c] = acc;
    }
}

// ------- fully fused: gather(f32) + (t4 = agg + agg@Wc1 + x@W3 + b4) + relu + @Wf + bf -------
// Gather: one wave64 per row, lane owns a float2; csr bounds wave-uniform (s_load path).
__global__ __launch_bounds__(256) void gather_fused(const int* __restrict__ off,
                                                    const int* __restrict__ end,
                                                    const int2* __restrict__ csr,
                                                    const float* __restrict__ W_edge,
                                                    const float* __restrict__ x,
                                                    const float* __restrict__ Wc1,
                                                    const float* __restrict__ W3,
                                                    const float* __restrict__ b4,
                                                    const float* __restrict__ Wf,
                                                    const float* __restrict__ bf,
                                                    float* __restrict__ out,
                                                    int nrows) {
    const int TR = 16;
    __shared__ float As[TR][H];
    __shared__ float Xs[TR][H];
    int row0 = blockIdx.x * TR;
    int tid = threadIdx.x;

    // load Xs (x rows)
    for (int i = tid; i < TR * H / 4; i += 256) {
        int fi = i * 4;
        int rr = fi >> 7, cc = fi & 127;
        float4 xv = {0.f, 0.f, 0.f, 0.f};
        if (row0 + rr < nrows)
            xv = *reinterpret_cast<const float4*>(&x[(long long)(row0 + rr) * H + cc]);
        *reinterpret_cast<float4*>(&Xs[rr][cc]) = xv;
    }

    // ---- phase A: gather. wave w handles rows 4w..4w+3, all 64 lanes on one row ----
    int wv = tid >> 6;
    int lane = tid & 63;
    int cl = lane * 2;
    #pragma unroll
    for (int rr4 = 0; rr4 < 4; ++rr4) {
        int rr = wv * 4 + rr4;
        int d = row0 + rr;
        float ax = 0.f, ay = 0.f;
        if (d < nrows) {
            int i0 = __builtin_amdgcn_readfirstlane(off[d]);
            int i1 = __builtin_amdgcn_readfirstlane(end[d]);
            int j = i0;
            for (; j + 4 <= i1; j += 4) {
                int2 e0 = csr[j];
                int2 e1 = csr[j + 1];
                int2 e2 = csr[j + 2];
                int2 e3 = csr[j + 3];
                float2 v0 = *reinterpret_cast<const float2*>(&W_edge[(long long)e0.x * H + cl]);
                float2 v1 = *reinterpret_cast<const float2*>(&W_edge[(long long)e1.x * H + cl]);
                float2 v2 = *reinterpret_cast<const float2*>(&W_edge[(long long)e2.x * H + cl]);
                float2 v3 = *reinterpret_cast<const float2*>(&W_edge[(long long)e3.x * H + cl]);
                float w0 = __int_as_float(e0.y), w1 = __int_as_float(e1.y);
                float w2 = __int_as_float(e2.y), w3 = __int_as_float(e3.y);
                ax += w0 * v0.x + w1 * v1.x + w2 * v2.x + w3 * v3.x;
                ay += w0 * v0.y + w1 * v1.y + w2 * v2.y + w3 * v3.y;
            }
            for (; j < i1; ++j) {
                int2 e = csr[j];
                float w = __int_as_float(e.y);
                float2 v = *reinterpret_cast<const float2*>(&W_edge[(long long)e.x * H + cl]);
                ax += w * v.x;
                ay += w * v.y;
            }
        }
        *reinterpret_cast<float2*>(&As[rr][cl]) = make_float2(ax, ay);
    }
    __syncthreads();

    // ---- phase B: t4 = agg + agg@Wc1 + x@W3 + b4 (v_pk_fma_f32) ----
    int c2 = (tid & 63) * 2;
    int rbase = (tid >> 6) * 4;
    f2 b4v = *reinterpret_cast<const f2*>(&b4[c2]);
    f2 acc[4];
    #pragma unroll
    for (int r = 0; r < 4; ++r)
        acc[r] = *reinterpret_cast<const f2*>(&As[rbase + r][c2]) + b4v;  // identity of (I+Wc1)

    for (int k = 0; k < H; k += 4) {
        f2 w1[4], w3[4];
        #pragma unroll
        for (int kk = 0; kk < 4; ++kk) {
            w1[kk] = *reinterpret_cast<const f2*>(&Wc1[(k + kk) * H + c2]);
            w3[kk] = *reinterpret_cast<const f2*>(&W3[(k + kk) * H + c2]);
        }
        #pragma unroll
        for (int r = 0; r < 4; ++r) {
            float4 a  = *reinterpret_cast<const float4*>(&As[rbase + r][k]);
            float4 xv = *reinterpret_cast<const float4*>(&Xs[rbase + r][k]);
            acc[r] = pkfma((f2){a.x, a.x}, w1[0], acc[r]);
            acc[r] = pkfma((f2){a.y, a.y}, w1[1], acc[r]);
            acc[r] = pkfma((f2){a.z, a.z}, w1[2], acc[r]);
            acc[r] = pkfma((f2){a.w, a.w}, w1[3], acc[r]);
            acc[r] = pkfma((f2){xv.x, xv.x}, w3[0], acc[r]);
            acc[r] = pkfma((f2){xv.y, xv.y}, w3[1], acc[r]);
            acc[r] = pkfma((f2){xv.z, xv.z}, w3[2], acc[r]);
            acc[r] = pkfma((f2){xv.w, xv.w}, w3[3], acc[r]);
        }
    }

    // ---- relu, stash back to LDS ----
    __syncthreads();
    #pragma unroll
    for (int r = 0; r < 4; ++r) {
        f2 z = {0.f, 0.f};
        *reinterpret_cast<f2*>(&As[rbase + r][c2]) = __builtin_elementwise_max(acc[r], z);
    }
    __syncthreads();

    // ---- phase C: out = relu(t4) @ Wf + bf ----
    f2 bfv = *reinterpret_cast<const f2*>(&bf[c2]);
    f2 acc2[4];
    #pragma unroll
    for (int r = 0; r < 4; ++r)
        acc2[r] = bfv;

    for (int k = 0; k < H; k += 4) {
        f2 wf[4];
        #pragma unroll
        for (int kk = 0; kk < 4; ++kk)
            wf[kk] = *reinterpret_cast<const f2*>(&Wf[(k + kk) * H + c2]);
        #pragma unroll
        for (int r = 0; r < 4; ++r) {
            float4 v = *reinterpret_cast<const float4*>(&As[rbase + r][k]);
            acc2[r] = pkfma((f2){v.x, v.x}, wf[0], acc2[r]);
            acc2[r] = pkfma((f2){v.y, v.y}, wf[1], acc2[r]);
            acc2[r] = pkfma((f2){v.z, v.z}, wf[2], acc2[r]);
            acc2[r] = pkfma((f2){v.w, v.w}, wf[3], acc2[r]);
        }
    }

    #pragma unroll
    for (int r = 0; r < 4; ++r) {
        int row = row0 + rbase + r;
        if (row < nrows)
            *reinterpret_cast<f2*>(&out[(long long)row * H + c2]) = acc2[r];
    }
}

extern "C" void kernel_launch(void* const* d_in, const int* in_sizes, int n_in,
                              void* d_out, int out_size, void* d_ws, size_t ws_size,
                              hipStream_t stream) {
    const float* x       = (const float*)d_in[0];
    const int*   ei      = (const int*)d_in[1];
    const float* ew      = (const float*)d_in[2];
    const float* W_edge  = (const float*)d_in[3];
    const float* b_edge  = (const float*)d_in[4];
    const float* W_node  = (const float*)d_in[5];
    const float* b_node  = (const float*)d_in[6];
    const float* W_cat1  = (const float*)d_in[7];
    const float* b_cat1  = (const float*)d_in[8];
    const float* W_cat2  = (const float*)d_in[9];
    const float* b_cat2  = (const float*)d_in[10];
    const float* W_final = (const float*)d_in[11];
    const float* b_final = (const float*)d_in[12];
    float* out = (float*)d_out;

    int*  deg  = (int*)d_ws;                 // NN
    int*  off  = deg + NN;                   // NN
    int*  cur  = off + NN;                   // NN
    int*  sums = cur + NN;                   // 512
    int2* csr  = (int2*)(sums + 512);        // NE (8B aligned: offset 1202048)
    float* W3  = (float*)(csr + NE);         // H*H
    float* b4  = W3 + H * H;                 // H

    // 1. CSR build
    zero_int<<<(NN + 255) / 256, 256, 0, stream>>>(deg, NN);
    hist_kernel<<<(NE + 255) / 256, 256, 0, stream>>>(ei, deg);
    scan_block<<<NB_SCAN, SCAN_CHUNK, 0, stream>>>(deg, off, sums, NN);
    scan_sums<<<1, 256, 0, stream>>>(sums, NB_SCAN);
    scan_add<<<(NN + 255) / 256, 256, 0, stream>>>(off, sums, cur, NN);
    fill_kernel<<<(NE + 255) / 256, 256, 0, stream>>>(ei, ew, cur, csr);

    // 2. merged precompute (W3 + b4)
    precompute_all<<<H + 1, H, 0, stream>>>(W_node, W_cat2, b_edge, W_cat1,
                                            b_node, b_cat1, b_cat2, W3, b4);

    // 3. fully fused gather + affine + relu + final linear -> d_out
    gather_fused<<<(NN + 15) / 16, 256, 0, stream>>>(off, cur, csr, W_edge, x,
                                                     W_cat1, W3, b4,
                                                     W_final, b_final, out, NN);
}

// Round 7
// 551.026 us; speedup vs baseline: 2.4135x; 2.4135x over previous
//
#include <hip/hip_runtime.h>

#define NN 100000
#define NE 1600000
#define H  128
#define SCAN_CHUNK 512
#define NB_SCAN ((NN + SCAN_CHUNK - 1) / SCAN_CHUNK)   // 196

// ---------------- zero int array ----------------
__global__ void zero_int(int* __restrict__ p, int n) {
    int i = blockIdx.x * blockDim.x + threadIdx.x;
    if (i < n) p[i] = 0;
}

// ---------------- histogram of dst ----------------
__global__ void hist_kernel(const int* __restrict__ ei, int* __restrict__ deg) {
    int e = blockIdx.x * 256 + threadIdx.x;
    if (e < NE) atomicAdd(&deg[ei[NE + e]], 1);
}

// ---------------- per-chunk exclusive scan ----------------
__global__ __launch_bounds__(SCAN_CHUNK) void scan_block(const int* __restrict__ deg,
                                                         int* __restrict__ off,
                                                         int* __restrict__ sums, int n) {
    __shared__ int buf[SCAN_CHUNK];
    int base = blockIdx.x * SCAN_CHUNK;
    int t = threadIdx.x;
    int v = (base + t < n) ? deg[base + t] : 0;
    buf[t] = v;
    __syncthreads();
    for (int s = 1; s < SCAN_CHUNK; s <<= 1) {
        int add = (t >= s) ? buf[t - s] : 0;
        __syncthreads();
        buf[t] += add;
        __syncthreads();
    }
    if (base + t < n) off[base + t] = buf[t] - v;
    if (t == SCAN_CHUNK - 1) sums[blockIdx.x] = buf[t];
}

__global__ __launch_bounds__(256) void scan_sums(int* __restrict__ sums, int nb) {
    __shared__ int buf[256];
    int t = threadIdx.x;
    int v = (t < nb) ? sums[t] : 0;
    buf[t] = v;
    __syncthreads();
    for (int s = 1; s < 256; s <<= 1) {
        int add = (t >= s) ? buf[t - s] : 0;
        __syncthreads();
        buf[t] += add;
        __syncthreads();
    }
    if (t < nb) sums[t] = buf[t] - v;
}

__global__ void scan_add(int* __restrict__ off, const int* __restrict__ sums,
                         int* __restrict__ cur, int n) {
    int i = blockIdx.x * 256 + threadIdx.x;
    if (i < n) {
        int v = off[i] + sums[i >> 9];
        off[i] = v;
        cur[i] = v;
    }
}

// ---------------- fill CSR with packed (src, weight) ----------------
__global__ void fill_kernel(const int* __restrict__ ei, const float* __restrict__ ew,
                            int* __restrict__ cur, int2* __restrict__ csr) {
    int e = blockIdx.x * 256 + threadIdx.x;
    if (e >= NE) return;
    int d = ei[NE + e];
    int pos = atomicAdd(&cur[d], 1);
    csr[pos] = make_int2(ei[e], __float_as_int(ew[e]));
}

// ---- merged precompute: blocks 0..127 -> W3 rows; block 128 -> b4 ----
__global__ __launch_bounds__(128) void precompute_all(const float* __restrict__ W_node,
                                                      const float* __restrict__ W_cat2,
                                                      const float* __restrict__ b_edge,
                                                      const float* __restrict__ W_cat1,
                                                      const float* __restrict__ b_node,
                                                      const float* __restrict__ b_cat1,
                                                      const float* __restrict__ b_cat2,
                                                      float* __restrict__ W3,
                                                      float* __restrict__ b4) {
    int c = threadIdx.x;
    if (blockIdx.x < H) {
        int k = blockIdx.x;
        __shared__ float wrow[H];
        wrow[c] = W_node[k * H + c];
        __syncthreads();
        float acc = wrow[c];   // identity part of (I + W_cat2)
        #pragma unroll 8
        for (int j = 0; j < H; ++j)
            acc += wrow[j] * W_cat2[j * H + c];
        W3[k * H + c] = acc;
    } else {
        __shared__ float be[H], bn[H];
        be[c] = b_edge[c];
        bn[c] = b_node[c];
        __syncthreads();
        float acc = be[c] + bn[c] + b_cat1[c] + b_cat2[c];
        for (int j = 0; j < H; ++j)
            acc += be[j] * W_cat1[j * H + c] + bn[j] * W_cat2[j * H + c];
        b4[c] = acc;
    }
}

// ------- fully fused: gather + (t4 = agg + agg@Wc1 + x@W3 + b4) + relu + @Wf + bf -------
// Gather: one wave64 per row, lane owns a float2. Rotated software pipeline:
// 8 W_edge loads in flight while the next 8 csr entries prefetch; tail edges are
// padded with (src=first, w=0) so the unrolled body is branch-free.
__global__ __launch_bounds__(256) void gather_fused(const int* __restrict__ off,
                                                    const int* __restrict__ end,
                                                    const int2* __restrict__ csr,
                                                    const float* __restrict__ W_edge,
                                                    const float* __restrict__ x,
                                                    const float* __restrict__ Wc1,
                                                    const float* __restrict__ W3,
                                                    const float* __restrict__ b4,
                                                    const float* __restrict__ Wf,
                                                    const float* __restrict__ bf,
                                                    float* __restrict__ out,
                                                    int nrows) {
    const int TR = 16;
    __shared__ float As[TR][H];
    __shared__ float Xs[TR][H];
    int row0 = blockIdx.x * TR;
    int tid = threadIdx.x;

    // load Xs (x rows)
    for (int i = tid; i < TR * H / 4; i += 256) {
        int fi = i * 4;
        int rr = fi >> 7, cc = fi & 127;
        float4 xv = {0.f, 0.f, 0.f, 0.f};
        if (row0 + rr < nrows)
            xv = *reinterpret_cast<const float4*>(&x[(long long)(row0 + rr) * H + cc]);
        *reinterpret_cast<float4*>(&Xs[rr][cc]) = xv;
    }

    // ---- phase A: pipelined gather. wave w handles rows 4w..4w+3 ----
    int wv = tid >> 6;
    int lane = tid & 63;
    int cl = lane * 2;
    #pragma unroll
    for (int rr4 = 0; rr4 < 4; ++rr4) {
        int rr = wv * 4 + rr4;
        int d = row0 + rr;
        float ax = 0.f, ay = 0.f;
        if (d < nrows) {
            int i0 = __builtin_amdgcn_readfirstlane(off[d]);
            int i1 = __builtin_amdgcn_readfirstlane(end[d]);
            if (i1 > i0) {
                int2 e[8];
                // prologue: load first chunk (clamped, zero-weight pad)
                #pragma unroll
                for (int u = 0; u < 8; ++u) {
                    int jj = i0 + u;
                    int2 t = csr[jj < i1 ? jj : i0];
                    if (jj >= i1) t.y = 0;
                    e[u] = t;
                }
                for (int j = i0; j < i1; j += 8) {
                    // 1) issue 8 independent W_edge loads for current chunk
                    float2 v[8];
                    float w[8];
                    #pragma unroll
                    for (int u = 0; u < 8; ++u) {
                        v[u] = *reinterpret_cast<const float2*>(
                                   &W_edge[(long long)e[u].x * H + cl]);
                        w[u] = __int_as_float(e[u].y);
                    }
                    // 2) prefetch next chunk's csr entries (hides under the vm loads)
                    #pragma unroll
                    for (int u = 0; u < 8; ++u) {
                        int jj = j + 8 + u;
                        int2 t = csr[jj < i1 ? jj : i0];
                        if (jj >= i1) t.y = 0;
                        e[u] = t;
                    }
                    // 3) consume current chunk
                    #pragma unroll
                    for (int u = 0; u < 8; ++u) {
                        ax += w[u] * v[u].x;
                        ay += w[u] * v[u].y;
                    }
                }
            }
        }
        *reinterpret_cast<float2*>(&As[rr][cl]) = make_float2(ax, ay);
    }
    __syncthreads();

    // ---- phase B: t4 = agg + agg@Wc1 + x@W3 + b4 (scalar, proven lean) ----
    int c2 = (tid & 63) * 2;
    int rbase = (tid >> 6) * 4;
    float2 b4v = *reinterpret_cast<const float2*>(&b4[c2]);
    float acc[4][2];
    #pragma unroll
    for (int r = 0; r < 4; ++r) {
        acc[r][0] = As[rbase + r][c2]     + b4v.x;   // identity term of (I + W_cat1)
        acc[r][1] = As[rbase + r][c2 + 1] + b4v.y;
    }

    for (int k = 0; k < H; k += 4) {
        float2 w1[4], w3[4];
        #pragma unroll
        for (int kk = 0; kk < 4; ++kk) {
            w1[kk] = *reinterpret_cast<const float2*>(&Wc1[(k + kk) * H + c2]);
            w3[kk] = *reinterpret_cast<const float2*>(&W3[(k + kk) * H + c2]);
        }
        #pragma unroll
        for (int r = 0; r < 4; ++r) {
            float4 a  = *reinterpret_cast<const float4*>(&As[rbase + r][k]);
            float4 xv = *reinterpret_cast<const float4*>(&Xs[rbase + r][k]);
            acc[r][0] += a.x * w1[0].x + a.y * w1[1].x + a.z * w1[2].x + a.w * w1[3].x
                       + xv.x * w3[0].x + xv.y * w3[1].x + xv.z * w3[2].x + xv.w * w3[3].x;
            acc[r][1] += a.x * w1[0].y + a.y * w1[1].y + a.z * w1[2].y + a.w * w1[3].y
                       + xv.x * w3[0].y + xv.y * w3[1].y + xv.z * w3[2].y + xv.w * w3[3].y;
        }
    }

    // ---- relu, stash back to LDS ----
    __syncthreads();
    #pragma unroll
    for (int r = 0; r < 4; ++r) {
        As[rbase + r][c2]     = fmaxf(acc[r][0], 0.f);
        As[rbase + r][c2 + 1] = fmaxf(acc[r][1], 0.f);
    }
    __syncthreads();

    // ---- phase C: out = relu(t4) @ Wf + bf ----
    float2 bfv = *reinterpret_cast<const float2*>(&bf[c2]);
    float acc2[4][2];
    #pragma unroll
    for (int r = 0; r < 4; ++r) {
        acc2[r][0] = bfv.x;
        acc2[r][1] = bfv.y;
    }

    for (int k = 0; k < H; k += 4) {
        float2 wf[4];
        #pragma unroll
        for (int kk = 0; kk < 4; ++kk)
            wf[kk] = *reinterpret_cast<const float2*>(&Wf[(k + kk) * H + c2]);
        #pragma unroll
        for (int r = 0; r < 4; ++r) {
            float4 v = *reinterpret_cast<const float4*>(&As[rbase + r][k]);
            acc2[r][0] += v.x * wf[0].x + v.y * wf[1].x + v.z * wf[2].x + v.w * wf[3].x;
            acc2[r][1] += v.x * wf[0].y + v.y * wf[1].y + v.z * wf[2].y + v.w * wf[3].y;
        }
    }

    #pragma unroll
    for (int r = 0; r < 4; ++r) {
        int row = row0 + rbase + r;
        if (row < nrows) {
            float2 o{acc2[r][0], acc2[r][1]};
            *reinterpret_cast<float2*>(&out[(long long)row * H + c2]) = o;
        }
    }
}

extern "C" void kernel_launch(void* const* d_in, const int* in_sizes, int n_in,
                              void* d_out, int out_size, void* d_ws, size_t ws_size,
                              hipStream_t stream) {
    const float* x       = (const float*)d_in[0];
    const int*   ei      = (const int*)d_in[1];
    const float* ew      = (const float*)d_in[2];
    const float* W_edge  = (const float*)d_in[3];
    const float* b_edge  = (const float*)d_in[4];
    const float* W_node  = (const float*)d_in[5];
    const float* b_node  = (const float*)d_in[6];
    const float* W_cat1  = (const float*)d_in[7];
    const float* b_cat1  = (const float*)d_in[8];
    const float* W_cat2  = (const float*)d_in[9];
    const float* b_cat2  = (const float*)d_in[10];
    const float* W_final = (const float*)d_in[11];
    const float* b_final = (const float*)d_in[12];
    float* out = (float*)d_out;

    int*  deg  = (int*)d_ws;                 // NN
    int*  off  = deg + NN;                   // NN
    int*  cur  = off + NN;                   // NN
    int*  sums = cur + NN;                   // 512
    int2* csr  = (int2*)(sums + 512);        // NE (8B aligned: offset 1202048)
    float* W3  = (float*)(csr + NE);         // H*H
    float* b4  = W3 + H * H;                 // H

    // 1. CSR build
    zero_int<<<(NN + 255) / 256, 256, 0, stream>>>(deg, NN);
    hist_kernel<<<(NE + 255) / 256, 256, 0, stream>>>(ei, deg);
    scan_block<<<NB_SCAN, SCAN_CHUNK, 0, stream>>>(deg, off, sums, NN);
    scan_sums<<<1, 256, 0, stream>>>(sums, NB_SCAN);
    scan_add<<<(NN + 255) / 256, 256, 0, stream>>>(off, sums, cur, NN);
    fill_kernel<<<(NE + 255) / 256, 256, 0, stream>>>(ei, ew, cur, csr);

    // 2. merged precompute (W3 + b4)
    precompute_all<<<H + 1, H, 0, stream>>>(W_node, W_cat2, b_edge, W_cat1,
                                            b_node, b_cat1, b_cat2, W3, b4);

    // 3. fully fused gather + affine + relu + final linear -> d_out
    gather_fused<<<(NN + 15) / 16, 256, 0, stream>>>(off, cur, csr, W_edge, x,
                                                     W_cat1, W3, b4,
                                                     W_final, b_final, out, NN);
}

// Round 8
// 526.381 us; speedup vs baseline: 2.5265x; 1.0468x over previous
//
#include <hip/hip_runtime.h>

#define NN 100000
#define NE 1600000
#define H  128
#define SCAN_CHUNK 512
#define NB_SCAN ((NN + SCAN_CHUNK - 1) / SCAN_CHUNK)   // 196

// ---------------- zero int array ----------------
__global__ void zero_int(int* __restrict__ p, int n) {
    int i = blockIdx.x * blockDim.x + threadIdx.x;
    if (i < n) p[i] = 0;
}

// ---------------- histogram of dst ----------------
__global__ void hist_kernel(const int* __restrict__ ei, int* __restrict__ deg) {
    int e = blockIdx.x * 256 + threadIdx.x;
    if (e < NE) atomicAdd(&deg[ei[NE + e]], 1);
}

// ---------------- per-chunk exclusive scan ----------------
__global__ __launch_bounds__(SCAN_CHUNK) void scan_block(const int* __restrict__ deg,
                                                         int* __restrict__ off,
                                                         int* __restrict__ sums, int n) {
    __shared__ int buf[SCAN_CHUNK];
    int base = blockIdx.x * SCAN_CHUNK;
    int t = threadIdx.x;
    int v = (base + t < n) ? deg[base + t] : 0;
    buf[t] = v;
    __syncthreads();
    for (int s = 1; s < SCAN_CHUNK; s <<= 1) {
        int add = (t >= s) ? buf[t - s] : 0;
        __syncthreads();
        buf[t] += add;
        __syncthreads();
    }
    if (base + t < n) off[base + t] = buf[t] - v;
    if (t == SCAN_CHUNK - 1) sums[blockIdx.x] = buf[t];
}

__global__ __launch_bounds__(256) void scan_sums(int* __restrict__ sums, int nb) {
    __shared__ int buf[256];
    int t = threadIdx.x;
    int v = (t < nb) ? sums[t] : 0;
    buf[t] = v;
    __syncthreads();
    for (int s = 1; s < 256; s <<= 1) {
        int add = (t >= s) ? buf[t - s] : 0;
        __syncthreads();
        buf[t] += add;
        __syncthreads();
    }
    if (t < nb) sums[t] = buf[t] - v;
}

__global__ void scan_add(int* __restrict__ off, const int* __restrict__ sums,
                         int* __restrict__ cur, int n) {
    int i = blockIdx.x * 256 + threadIdx.x;
    if (i < n) {
        int v = off[i] + sums[i >> 9];
        off[i] = v;
        cur[i] = v;
    }
}

// ---------------- fill CSR with packed (src, weight) ----------------
__global__ void fill_kernel(const int* __restrict__ ei, const float* __restrict__ ew,
                            int* __restrict__ cur, int2* __restrict__ csr) {
    int e = blockIdx.x * 256 + threadIdx.x;
    if (e >= NE) return;
    int d = ei[NE + e];
    int pos = atomicAdd(&cur[d], 1);
    csr[pos] = make_int2(ei[e], __float_as_int(ew[e]));
}

// ---------------- convert W_edge f32 -> packed bf16 (RNE) ----------------
// out[i] packs channels (2i, 2i+1): low 16 bits = even channel, high = odd.
__global__ void conv_bf16(const float* __restrict__ in, unsigned int* __restrict__ outp,
                          int n2) {
    int i = blockIdx.x * 256 + threadIdx.x;
    if (i >= n2) return;
    float2 v = *reinterpret_cast<const float2*>(&in[(long long)i * 2]);
    unsigned int b0 = __float_as_uint(v.x);
    unsigned int b1 = __float_as_uint(v.y);
    b0 = (b0 + 0x7fffu + ((b0 >> 16) & 1u)) >> 16;
    b1 = (b1 + 0x7fffu + ((b1 >> 16) & 1u)) >> 16;
    outp[i] = b0 | (b1 << 16);
}

// ---- merged precompute: blocks 0..127 -> W3 rows; block 128 -> b4 ----
__global__ __launch_bounds__(128) void precompute_all(const float* __restrict__ W_node,
                                                      const float* __restrict__ W_cat2,
                                                      const float* __restrict__ b_edge,
                                                      const float* __restrict__ W_cat1,
                                                      const float* __restrict__ b_node,
                                                      const float* __restrict__ b_cat1,
                                                      const float* __restrict__ b_cat2,
                                                      float* __restrict__ W3,
                                                      float* __restrict__ b4) {
    int c = threadIdx.x;
    if (blockIdx.x < H) {
        int k = blockIdx.x;
        __shared__ float wrow[H];
        wrow[c] = W_node[k * H + c];
        __syncthreads();
        float acc = wrow[c];   // identity part of (I + W_cat2)
        #pragma unroll 8
        for (int j = 0; j < H; ++j)
            acc += wrow[j] * W_cat2[j * H + c];
        W3[k * H + c] = acc;
    } else {
        __shared__ float be[H], bn[H];
        be[c] = b_edge[c];
        bn[c] = b_node[c];
        __syncthreads();
        float acc = be[c] + bn[c] + b_cat1[c] + b_cat2[c];
        for (int j = 0; j < H; ++j)
            acc += be[j] * W_cat1[j * H + c] + bn[j] * W_cat2[j * H + c];
        b4[c] = acc;
    }
}

// ------- fully fused: gather(bf16) + (t4 = agg + agg@Wc1 + x@W3 + b4) + relu + @Wf + bf -------
// Gather: one wave64 per row, lane owns one packed-bf16 channel pair (4 B/lane,
// 256 B/edge). Scalar f32 accumulation; scalar phases B/C (proven VGPR~32 codegen).
__global__ __launch_bounds__(256) void gather_fused(const int* __restrict__ off,
                                                    const int* __restrict__ end,
                                                    const int2* __restrict__ csr,
                                                    const unsigned int* __restrict__ wbf,
                                                    const float* __restrict__ x,
                                                    const float* __restrict__ Wc1,
                                                    const float* __restrict__ W3,
                                                    const float* __restrict__ b4,
                                                    const float* __restrict__ Wf,
                                                    const float* __restrict__ bf,
                                                    float* __restrict__ out,
                                                    int nrows) {
    const int TR = 16;
    __shared__ float As[TR][H];
    __shared__ float Xs[TR][H];
    int row0 = blockIdx.x * TR;
    int tid = threadIdx.x;

    // load Xs (x rows)
    for (int i = tid; i < TR * H / 4; i += 256) {
        int fi = i * 4;
        int rr = fi >> 7, cc = fi & 127;
        float4 xv = {0.f, 0.f, 0.f, 0.f};
        if (row0 + rr < nrows)
            xv = *reinterpret_cast<const float4*>(&x[(long long)(row0 + rr) * H + cc]);
        *reinterpret_cast<float4*>(&Xs[rr][cc]) = xv;
    }

    // ---- phase A: gather (bf16 rows). wave w handles rows 4w..4w+3 ----
    int wv = tid >> 6;
    int lane = tid & 63;
    #pragma unroll
    for (int rr4 = 0; rr4 < 4; ++rr4) {
        int rr = wv * 4 + rr4;
        int d = row0 + rr;
        float ax = 0.f, ay = 0.f;
        if (d < nrows) {
            int i0 = __builtin_amdgcn_readfirstlane(off[d]);
            int i1 = __builtin_amdgcn_readfirstlane(end[d]);
            int j = i0;
            for (; j + 4 <= i1; j += 4) {
                int2 e0 = csr[j];
                int2 e1 = csr[j + 1];
                int2 e2 = csr[j + 2];
                int2 e3 = csr[j + 3];
                unsigned int u0 = wbf[(long long)e0.x * 64 + lane];
                unsigned int u1 = wbf[(long long)e1.x * 64 + lane];
                unsigned int u2 = wbf[(long long)e2.x * 64 + lane];
                unsigned int u3 = wbf[(long long)e3.x * 64 + lane];
                float w0 = __int_as_float(e0.y), w1 = __int_as_float(e1.y);
                float w2 = __int_as_float(e2.y), w3 = __int_as_float(e3.y);
                ax += w0 * __uint_as_float(u0 << 16) + w1 * __uint_as_float(u1 << 16)
                    + w2 * __uint_as_float(u2 << 16) + w3 * __uint_as_float(u3 << 16);
                ay += w0 * __uint_as_float(u0 & 0xffff0000u) + w1 * __uint_as_float(u1 & 0xffff0000u)
                    + w2 * __uint_as_float(u2 & 0xffff0000u) + w3 * __uint_as_float(u3 & 0xffff0000u);
            }
            for (; j < i1; ++j) {
                int2 e = csr[j];
                float w = __int_as_float(e.y);
                unsigned int u = wbf[(long long)e.x * 64 + lane];
                ax += w * __uint_as_float(u << 16);
                ay += w * __uint_as_float(u & 0xffff0000u);
            }
        }
        *reinterpret_cast<float2*>(&As[rr][lane * 2]) = make_float2(ax, ay);
    }
    __syncthreads();

    // ---- phase B: t4 = agg + agg@Wc1 + x@W3 + b4 (scalar, proven lean) ----
    int c2 = (tid & 63) * 2;
    int rbase = (tid >> 6) * 4;
    float2 b4v = *reinterpret_cast<const float2*>(&b4[c2]);
    float acc[4][2];
    #pragma unroll
    for (int r = 0; r < 4; ++r) {
        acc[r][0] = As[rbase + r][c2]     + b4v.x;   // identity term of (I + W_cat1)
        acc[r][1] = As[rbase + r][c2 + 1] + b4v.y;
    }

    for (int k = 0; k < H; k += 4) {
        float2 w1[4], w3[4];
        #pragma unroll
        for (int kk = 0; kk < 4; ++kk) {
            w1[kk] = *reinterpret_cast<const float2*>(&Wc1[(k + kk) * H + c2]);
            w3[kk] = *reinterpret_cast<const float2*>(&W3[(k + kk) * H + c2]);
        }
        #pragma unroll
        for (int r = 0; r < 4; ++r) {
            float4 a  = *reinterpret_cast<const float4*>(&As[rbase + r][k]);
            float4 xv = *reinterpret_cast<const float4*>(&Xs[rbase + r][k]);
            acc[r][0] += a.x * w1[0].x + a.y * w1[1].x + a.z * w1[2].x + a.w * w1[3].x
                       + xv.x * w3[0].x + xv.y * w3[1].x + xv.z * w3[2].x + xv.w * w3[3].x;
            acc[r][1] += a.x * w1[0].y + a.y * w1[1].y + a.z * w1[2].y + a.w * w1[3].y
                       + xv.x * w3[0].y + xv.y * w3[1].y + xv.z * w3[2].y + xv.w * w3[3].y;
        }
    }

    // ---- relu, stash back to LDS ----
    __syncthreads();
    #pragma unroll
    for (int r = 0; r < 4; ++r) {
        As[rbase + r][c2]     = fmaxf(acc[r][0], 0.f);
        As[rbase + r][c2 + 1] = fmaxf(acc[r][1], 0.f);
    }
    __syncthreads();

    // ---- phase C: out = relu(t4) @ Wf + bf ----
    float2 bfv = *reinterpret_cast<const float2*>(&bf[c2]);
    float acc2[4][2];
    #pragma unroll
    for (int r = 0; r < 4; ++r) {
        acc2[r][0] = bfv.x;
        acc2[r][1] = bfv.y;
    }

    for (int k = 0; k < H; k += 4) {
        float2 wf[4];
        #pragma unroll
        for (int kk = 0; kk < 4; ++kk)
            wf[kk] = *reinterpret_cast<const float2*>(&Wf[(k + kk) * H + c2]);
        #pragma unroll
        for (int r = 0; r < 4; ++r) {
            float4 v = *reinterpret_cast<const float4*>(&As[rbase + r][k]);
            acc2[r][0] += v.x * wf[0].x + v.y * wf[1].x + v.z * wf[2].x + v.w * wf[3].x;
            acc2[r][1] += v.x * wf[0].y + v.y * wf[1].y + v.z * wf[2].y + v.w * wf[3].y;
        }
    }

    #pragma unroll
    for (int r = 0; r < 4; ++r) {
        int row = row0 + rbase + r;
        if (row < nrows) {
            float2 o{acc2[r][0], acc2[r][1]};
            *reinterpret_cast<float2*>(&out[(long long)row * H + c2]) = o;
        }
    }
}

extern "C" void kernel_launch(void* const* d_in, const int* in_sizes, int n_in,
                              void* d_out, int out_size, void* d_ws, size_t ws_size,
                              hipStream_t stream) {
    const float* x       = (const float*)d_in[0];
    const int*   ei      = (const int*)d_in[1];
    const float* ew      = (const float*)d_in[2];
    const float* W_edge  = (const float*)d_in[3];
    const float* b_edge  = (const float*)d_in[4];
    const float* W_node  = (const float*)d_in[5];
    const float* b_node  = (const float*)d_in[6];
    const float* W_cat1  = (const float*)d_in[7];
    const float* b_cat1  = (const float*)d_in[8];
    const float* W_cat2  = (const float*)d_in[9];
    const float* b_cat2  = (const float*)d_in[10];
    const float* W_final = (const float*)d_in[11];
    const float* b_final = (const float*)d_in[12];
    float* out = (float*)d_out;

    // workspace layout
    int*  deg  = (int*)d_ws;                         // NN
    int*  off  = deg + NN;                           // NN
    int*  cur  = off + NN;                           // NN
    int*  sums = cur + NN;                           // 512
    int2* csr  = (int2*)(sums + 512);                // NE   (8B aligned: offset 1202048)
    unsigned int* wbf = (unsigned int*)(csr + NE);   // NN*64 packed bf16 pairs (25.6 MB)
    float* W3  = (float*)(wbf + (size_t)NN * 64);    // H*H
    float* b4  = W3 + H * H;                         // H

    // 1. CSR build
    zero_int<<<(NN + 255) / 256, 256, 0, stream>>>(deg, NN);
    hist_kernel<<<(NE + 255) / 256, 256, 0, stream>>>(ei, deg);
    scan_block<<<NB_SCAN, SCAN_CHUNK, 0, stream>>>(deg, off, sums, NN);
    scan_sums<<<1, 256, 0, stream>>>(sums, NB_SCAN);
    scan_add<<<(NN + 255) / 256, 256, 0, stream>>>(off, sums, cur, NN);
    fill_kernel<<<(NE + 255) / 256, 256, 0, stream>>>(ei, ew, cur, csr);

    // 2. W_edge -> bf16, merged precompute (W3 + b4)
    conv_bf16<<<(NN * H / 2 + 255) / 256, 256, 0, stream>>>(W_edge, wbf, NN * H / 2);
    precompute_all<<<H + 1, H, 0, stream>>>(W_node, W_cat2, b_edge, W_cat1,
                                            b_node, b_cat1, b_cat2, W3, b4);

    // 3. fully fused gather + affine + relu + final linear -> d_out
    gather_fused<<<(NN + 15) / 16, 256, 0, stream>>>(off, cur, csr, wbf, x,
                                                     W_cat1, W3, b4,
                                                     W_final, b_final, out, NN);
}

// Round 9
// 523.327 us; speedup vs baseline: 2.5412x; 1.0058x over previous
//
#include <hip/hip_runtime.h>

#define NN 100000
#define NE 1600000
#define H  128
#define SCAN_CHUNK 512
#define NB_SCAN ((NN + SCAN_CHUNK - 1) / SCAN_CHUNK)   // 196

// ---------------- zero int array ----------------
__global__ void zero_int(int* __restrict__ p, int n) {
    int i = blockIdx.x * blockDim.x + threadIdx.x;
    if (i < n) p[i] = 0;
}

// ---------------- histogram of dst ----------------
__global__ void hist_kernel(const int* __restrict__ ei, int* __restrict__ deg) {
    int e = blockIdx.x * 256 + threadIdx.x;
    if (e < NE) atomicAdd(&deg[ei[NE + e]], 1);
}

// ---------------- per-chunk exclusive scan ----------------
__global__ __launch_bounds__(SCAN_CHUNK) void scan_block(const int* __restrict__ deg,
                                                         int* __restrict__ off,
                                                         int* __restrict__ sums, int n) {
    __shared__ int buf[SCAN_CHUNK];
    int base = blockIdx.x * SCAN_CHUNK;
    int t = threadIdx.x;
    int v = (base + t < n) ? deg[base + t] : 0;
    buf[t] = v;
    __syncthreads();
    for (int s = 1; s < SCAN_CHUNK; s <<= 1) {
        int add = (t >= s) ? buf[t - s] : 0;
        __syncthreads();
        buf[t] += add;
        __syncthreads();
    }
    if (base + t < n) off[base + t] = buf[t] - v;
    if (t == SCAN_CHUNK - 1) sums[blockIdx.x] = buf[t];
}

__global__ __launch_bounds__(256) void scan_sums(int* __restrict__ sums, int nb) {
    __shared__ int buf[256];
    int t = threadIdx.x;
    int v = (t < nb) ? sums[t] : 0;
    buf[t] = v;
    __syncthreads();
    for (int s = 1; s < 256; s <<= 1) {
        int add = (t >= s) ? buf[t - s] : 0;
        __syncthreads();
        buf[t] += add;
        __syncthreads();
    }
    if (t < nb) sums[t] = buf[t] - v;
}

__global__ void scan_add(int* __restrict__ off, const int* __restrict__ sums,
                         int* __restrict__ cur, int n) {
    int i = blockIdx.x * 256 + threadIdx.x;
    if (i < n) {
        int v = off[i] + sums[i >> 9];
        off[i] = v;
        cur[i] = v;
    }
}

// ---------------- fill CSR with packed (src, weight) ----------------
__global__ void fill_kernel(const int* __restrict__ ei, const float* __restrict__ ew,
                            int* __restrict__ cur, int2* __restrict__ csr) {
    int e = blockIdx.x * 256 + threadIdx.x;
    if (e >= NE) return;
    int d = ei[NE + e];
    int pos = atomicAdd(&cur[d], 1);
    csr[pos] = make_int2(ei[e], __float_as_int(ew[e]));
}

// ---------------- convert W_edge f32 -> packed bf16 (RNE) ----------------
__global__ void conv_bf16(const float* __restrict__ in, unsigned int* __restrict__ outp,
                          int n2) {
    int i = blockIdx.x * 256 + threadIdx.x;
    if (i >= n2) return;
    float2 v = *reinterpret_cast<const float2*>(&in[(long long)i * 2]);
    unsigned int b0 = __float_as_uint(v.x);
    unsigned int b1 = __float_as_uint(v.y);
    b0 = (b0 + 0x7fffu + ((b0 >> 16) & 1u)) >> 16;
    b1 = (b1 + 0x7fffu + ((b1 >> 16) & 1u)) >> 16;
    outp[i] = b0 | (b1 << 16);
}

// ---- merged precompute: blocks 0..127 -> W3 rows; block 128 -> b4 ----
__global__ __launch_bounds__(128) void precompute_all(const float* __restrict__ W_node,
                                                      const float* __restrict__ W_cat2,
                                                      const float* __restrict__ b_edge,
                                                      const float* __restrict__ W_cat1,
                                                      const float* __restrict__ b_node,
                                                      const float* __restrict__ b_cat1,
                                                      const float* __restrict__ b_cat2,
                                                      float* __restrict__ W3,
                                                      float* __restrict__ b4) {
    int c = threadIdx.x;
    if (blockIdx.x < H) {
        int k = blockIdx.x;
        __shared__ float wrow[H];
        wrow[c] = W_node[k * H + c];
        __syncthreads();
        float acc = wrow[c];   // identity part of (I + W_cat2)
        #pragma unroll 8
        for (int j = 0; j < H; ++j)
            acc += wrow[j] * W_cat2[j * H + c];
        W3[k * H + c] = acc;
    } else {
        __shared__ float be[H], bn[H];
        be[c] = b_edge[c];
        bn[c] = b_node[c];
        __syncthreads();
        float acc = be[c] + bn[c] + b_cat1[c] + b_cat2[c];
        for (int j = 0; j < H; ++j)
            acc += be[j] * W_cat1[j * H + c] + bn[j] * W_cat2[j * H + c];
        b4[c] = acc;
    }
}

// ------- fully fused: gather(bf16, 8-deep pipelined) + affine + relu + final -------
// launch_bounds(256,3): VGPR budget ~170 so the allocator can keep 8 loads in
// flight (previous rounds pinned VGPR=32 and serialized the pipeline).
__global__ __launch_bounds__(256, 3) void gather_fused(const int* __restrict__ off,
                                                       const int* __restrict__ end,
                                                       const int2* __restrict__ csr,
                                                       const unsigned int* __restrict__ wbf,
                                                       const float* __restrict__ x,
                                                       const float* __restrict__ Wc1,
                                                       const float* __restrict__ W3,
                                                       const float* __restrict__ b4,
                                                       const float* __restrict__ Wf,
                                                       const float* __restrict__ bf,
                                                       float* __restrict__ out,
                                                       int nrows) {
    const int TR = 16;
    __shared__ float As[TR][H];
    __shared__ float Xs[TR][H];
    int row0 = blockIdx.x * TR;
    int tid = threadIdx.x;

    // load Xs (x rows)
    for (int i = tid; i < TR * H / 4; i += 256) {
        int fi = i * 4;
        int rr = fi >> 7, cc = fi & 127;
        float4 xv = {0.f, 0.f, 0.f, 0.f};
        if (row0 + rr < nrows)
            xv = *reinterpret_cast<const float4*>(&x[(long long)(row0 + rr) * H + cc]);
        *reinterpret_cast<float4*>(&Xs[rr][cc]) = xv;
    }

    // ---- phase A: 8-deep rotated-pipeline gather (bf16 rows, 256B/edge) ----
    int wv = tid >> 6;
    int lane = tid & 63;
    #pragma unroll
    for (int rr4 = 0; rr4 < 4; ++rr4) {
        int rr = wv * 4 + rr4;
        int d = row0 + rr;
        float ax = 0.f, ay = 0.f;
        if (d < nrows) {
            int i0 = __builtin_amdgcn_readfirstlane(off[d]);
            int i1 = __builtin_amdgcn_readfirstlane(end[d]);
            if (i1 > i0) {
                int2 e[8];
                // prologue: first chunk of csr entries (clamped, zero-weight pad)
                #pragma unroll
                for (int u = 0; u < 8; ++u) {
                    int jj = i0 + u;
                    int2 t = csr[jj < i1 ? jj : i0];
                    if (jj >= i1) t.y = 0;
                    e[u] = t;
                }
                for (int j = i0; j < i1; j += 8) {
                    // 1) issue 8 independent W_edge(bf16) loads for current chunk
                    unsigned int uu[8];
                    float w[8];
                    #pragma unroll
                    for (int u = 0; u < 8; ++u) {
                        uu[u] = wbf[(long long)e[u].x * 64 + lane];
                        w[u]  = __int_as_float(e[u].y);
                    }
                    // 2) prefetch next chunk's csr entries (hides under vm loads)
                    #pragma unroll
                    for (int u = 0; u < 8; ++u) {
                        int jj = j + 8 + u;
                        int2 t = csr[jj < i1 ? jj : i0];
                        if (jj >= i1) t.y = 0;
                        e[u] = t;
                    }
                    // 3) consume current chunk
                    #pragma unroll
                    for (int u = 0; u < 8; ++u) {
                        ax += w[u] * __uint_as_float(uu[u] << 16);
                        ay += w[u] * __uint_as_float(uu[u] & 0xffff0000u);
                    }
                }
            }
        }
        *reinterpret_cast<float2*>(&As[rr][lane * 2]) = make_float2(ax, ay);
    }
    __syncthreads();

    // ---- phase B: t4 = agg + agg@Wc1 + x@W3 + b4 (scalar, proven lean) ----
    int c2 = (tid & 63) * 2;
    int rbase = (tid >> 6) * 4;
    float2 b4v = *reinterpret_cast<const float2*>(&b4[c2]);
    float acc[4][2];
    #pragma unroll
    for (int r = 0; r < 4; ++r) {
        acc[r][0] = As[rbase + r][c2]     + b4v.x;   // identity term of (I + W_cat1)
        acc[r][1] = As[rbase + r][c2 + 1] + b4v.y;
    }

    for (int k = 0; k < H; k += 4) {
        float2 w1[4], w3[4];
        #pragma unroll
        for (int kk = 0; kk < 4; ++kk) {
            w1[kk] = *reinterpret_cast<const float2*>(&Wc1[(k + kk) * H + c2]);
            w3[kk] = *reinterpret_cast<const float2*>(&W3[(k + kk) * H + c2]);
        }
        #pragma unroll
        for (int r = 0; r < 4; ++r) {
            float4 a  = *reinterpret_cast<const float4*>(&As[rbase + r][k]);
            float4 xv = *reinterpret_cast<const float4*>(&Xs[rbase + r][k]);
            acc[r][0] += a.x * w1[0].x + a.y * w1[1].x + a.z * w1[2].x + a.w * w1[3].x
                       + xv.x * w3[0].x + xv.y * w3[1].x + xv.z * w3[2].x + xv.w * w3[3].x;
            acc[r][1] += a.x * w1[0].y + a.y * w1[1].y + a.z * w1[2].y + a.w * w1[3].y
                       + xv.x * w3[0].y + xv.y * w3[1].y + xv.z * w3[2].y + xv.w * w3[3].y;
        }
    }

    // ---- relu, stash back to LDS ----
    __syncthreads();
    #pragma unroll
    for (int r = 0; r < 4; ++r) {
        As[rbase + r][c2]     = fmaxf(acc[r][0], 0.f);
        As[rbase + r][c2 + 1] = fmaxf(acc[r][1], 0.f);
    }
    __syncthreads();

    // ---- phase C: out = relu(t4) @ Wf + bf ----
    float2 bfv = *reinterpret_cast<const float2*>(&bf[c2]);
    float acc2[4][2];
    #pragma unroll
    for (int r = 0; r < 4; ++r) {
        acc2[r][0] = bfv.x;
        acc2[r][1] = bfv.y;
    }

    for (int k = 0; k < H; k += 4) {
        float2 wf[4];
        #pragma unroll
        for (int kk = 0; kk < 4; ++kk)
            wf[kk] = *reinterpret_cast<const float2*>(&Wf[(k + kk) * H + c2]);
        #pragma unroll
        for (int r = 0; r < 4; ++r) {
            float4 v = *reinterpret_cast<const float4*>(&As[rbase + r][k]);
            acc2[r][0] += v.x * wf[0].x + v.y * wf[1].x + v.z * wf[2].x + v.w * wf[3].x;
            acc2[r][1] += v.x * wf[0].y + v.y * wf[1].y + v.z * wf[2].y + v.w * wf[3].y;
        }
    }

    #pragma unroll
    for (int r = 0; r < 4; ++r) {
        int row = row0 + rbase + r;
        if (row < nrows) {
            float2 o{acc2[r][0], acc2[r][1]};
            *reinterpret_cast<float2*>(&out[(long long)row * H + c2]) = o;
        }
    }
}

extern "C" void kernel_launch(void* const* d_in, const int* in_sizes, int n_in,
                              void* d_out, int out_size, void* d_ws, size_t ws_size,
                              hipStream_t stream) {
    const float* x       = (const float*)d_in[0];
    const int*   ei      = (const int*)d_in[1];
    const float* ew      = (const float*)d_in[2];
    const float* W_edge  = (const float*)d_in[3];
    const float* b_edge  = (const float*)d_in[4];
    const float* W_node  = (const float*)d_in[5];
    const float* b_node  = (const float*)d_in[6];
    const float* W_cat1  = (const float*)d_in[7];
    const float* b_cat1  = (const float*)d_in[8];
    const float* W_cat2  = (const float*)d_in[9];
    const float* b_cat2  = (const float*)d_in[10];
    const float* W_final = (const float*)d_in[11];
    const float* b_final = (const float*)d_in[12];
    float* out = (float*)d_out;

    // workspace layout
    int*  deg  = (int*)d_ws;                         // NN
    int*  off  = deg + NN;                           // NN
    int*  cur  = off + NN;                           // NN
    int*  sums = cur + NN;                           // 512
    int2* csr  = (int2*)(sums + 512);                // NE   (8B aligned: offset 1202048)
    unsigned int* wbf = (unsigned int*)(csr + NE);   // NN*64 packed bf16 pairs (25.6 MB)
    float* W3  = (float*)(wbf + (size_t)NN * 64);    // H*H
    float* b4  = W3 + H * H;                         // H

    // 1. CSR build
    zero_int<<<(NN + 255) / 256, 256, 0, stream>>>(deg, NN);
    hist_kernel<<<(NE + 255) / 256, 256, 0, stream>>>(ei, deg);
    scan_block<<<NB_SCAN, SCAN_CHUNK, 0, stream>>>(deg, off, sums, NN);
    scan_sums<<<1, 256, 0, stream>>>(sums, NB_SCAN);
    scan_add<<<(NN + 255) / 256, 256, 0, stream>>>(off, sums, cur, NN);
    fill_kernel<<<(NE + 255) / 256, 256, 0, stream>>>(ei, ew, cur, csr);

    // 2. W_edge -> bf16, merged precompute (W3 + b4)
    conv_bf16<<<(NN * H / 2 + 255) / 256, 256, 0, stream>>>(W_edge, wbf, NN * H / 2);
    precompute_all<<<H + 1, H, 0, stream>>>(W_node, W_cat2, b_edge, W_cat1,
                                            b_node, b_cat1, b_cat2, W3, b4);

    // 3. fully fused gather + affine + relu + final linear -> d_out
    gather_fused<<<(NN + 15) / 16, 256, 0, stream>>>(off, cur, csr, wbf, x,
                                                     W_cat1, W3, b4,
                                                     W_final, b_final, out, NN);
}

// Round 10
// 521.757 us; speedup vs baseline: 2.5489x; 1.0030x over previous
//
#include <hip/hip_runtime.h>

#define NN 100000
#define NE 1600000
#define H  128
#define SCAN_CHUNK 512
#define NB_SCAN ((NN + SCAN_CHUNK - 1) / SCAN_CHUNK)   // 196

// ---------------- zero int array ----------------
__global__ void zero_int(int* __restrict__ p, int n) {
    int i = blockIdx.x * blockDim.x + threadIdx.x;
    if (i < n) p[i] = 0;
}

// ---------------- histogram of dst ----------------
__global__ void hist_kernel(const int* __restrict__ ei, int* __restrict__ deg) {
    int e = blockIdx.x * 256 + threadIdx.x;
    if (e < NE) atomicAdd(&deg[ei[NE + e]], 1);
}

// ---------------- per-chunk exclusive scan ----------------
__global__ __launch_bounds__(SCAN_CHUNK) void scan_block(const int* __restrict__ deg,
                                                         int* __restrict__ off,
                                                         int* __restrict__ sums, int n) {
    __shared__ int buf[SCAN_CHUNK];
    int base = blockIdx.x * SCAN_CHUNK;
    int t = threadIdx.x;
    int v = (base + t < n) ? deg[base + t] : 0;
    buf[t] = v;
    __syncthreads();
    for (int s = 1; s < SCAN_CHUNK; s <<= 1) {
        int add = (t >= s) ? buf[t - s] : 0;
        __syncthreads();
        buf[t] += add;
        __syncthreads();
    }
    if (base + t < n) off[base + t] = buf[t] - v;
    if (t == SCAN_CHUNK - 1) sums[blockIdx.x] = buf[t];
}

__global__ __launch_bounds__(256) void scan_sums(int* __restrict__ sums, int nb) {
    __shared__ int buf[256];
    int t = threadIdx.x;
    int v = (t < nb) ? sums[t] : 0;
    buf[t] = v;
    __syncthreads();
    for (int s = 1; s < 256; s <<= 1) {
        int add = (t >= s) ? buf[t - s] : 0;
        __syncthreads();
        buf[t] += add;
        __syncthreads();
    }
    if (t < nb) sums[t] = buf[t] - v;
}

__global__ void scan_add(int* __restrict__ off, const int* __restrict__ sums,
                         int* __restrict__ cur, int n) {
    int i = blockIdx.x * 256 + threadIdx.x;
    if (i < n) {
        int v = off[i] + sums[i >> 9];
        off[i] = v;
        cur[i] = v;
    }
}

// ---------------- fill CSR with packed (src, weight) ----------------
__global__ void fill_kernel(const int* __restrict__ ei, const float* __restrict__ ew,
                            int* __restrict__ cur, int2* __restrict__ csr) {
    int e = blockIdx.x * 256 + threadIdx.x;
    if (e >= NE) return;
    int d = ei[NE + e];
    int pos = atomicAdd(&cur[d], 1);
    csr[pos] = make_int2(ei[e], __float_as_int(ew[e]));
}

// ---------------- convert W_edge f32 -> packed bf16 (RNE) ----------------
__global__ void conv_bf16(const float* __restrict__ in, unsigned int* __restrict__ outp,
                          int n2) {
    int i = blockIdx.x * 256 + threadIdx.x;
    if (i >= n2) return;
    float2 v = *reinterpret_cast<const float2*>(&in[(long long)i * 2]);
    unsigned int b0 = __float_as_uint(v.x);
    unsigned int b1 = __float_as_uint(v.y);
    b0 = (b0 + 0x7fffu + ((b0 >> 16) & 1u)) >> 16;
    b1 = (b1 + 0x7fffu + ((b1 >> 16) & 1u)) >> 16;
    outp[i] = b0 | (b1 << 16);
}

// ---- merged precompute: blocks 0..127 -> W3 rows; block 128 -> b4 ----
__global__ __launch_bounds__(128) void precompute_all(const float* __restrict__ W_node,
                                                      const float* __restrict__ W_cat2,
                                                      const float* __restrict__ b_edge,
                                                      const float* __restrict__ W_cat1,
                                                      const float* __restrict__ b_node,
                                                      const float* __restrict__ b_cat1,
                                                      const float* __restrict__ b_cat2,
                                                      float* __restrict__ W3,
                                                      float* __restrict__ b4) {
    int c = threadIdx.x;
    if (blockIdx.x < H) {
        int k = blockIdx.x;
        __shared__ float wrow[H];
        wrow[c] = W_node[k * H + c];
        __syncthreads();
        float acc = wrow[c];   // identity part of (I + W_cat2)
        #pragma unroll 8
        for (int j = 0; j < H; ++j)
            acc += wrow[j] * W_cat2[j * H + c];
        W3[k * H + c] = acc;
    } else {
        __shared__ float be[H], bn[H];
        be[c] = b_edge[c];
        bn[c] = b_node[c];
        __syncthreads();
        float acc = be[c] + bn[c] + b_cat1[c] + b_cat2[c];
        for (int j = 0; j < H; ++j)
            acc += be[j] * W_cat1[j * H + c] + bn[j] * W_cat2[j * H + c];
        b4[c] = acc;
    }
}

// ------- fully fused: gather(bf16, L1-bypass sc0 loads) + affine + relu + final -------
__global__ __launch_bounds__(256, 3) void gather_fused(const int* __restrict__ off,
                                                       const int* __restrict__ end,
                                                       const int2* __restrict__ csr,
                                                       const unsigned int* __restrict__ wbf,
                                                       const float* __restrict__ x,
                                                       const float* __restrict__ Wc1,
                                                       const float* __restrict__ W3,
                                                       const float* __restrict__ b4,
                                                       const float* __restrict__ Wf,
                                                       const float* __restrict__ bf,
                                                       float* __restrict__ out,
                                                       int nrows) {
    const int TR = 16;
    __shared__ float As[TR][H];
    __shared__ float Xs[TR][H];
    int row0 = blockIdx.x * TR;
    int tid = threadIdx.x;

    // load Xs (x rows)
    for (int i = tid; i < TR * H / 4; i += 256) {
        int fi = i * 4;
        int rr = fi >> 7, cc = fi & 127;
        float4 xv = {0.f, 0.f, 0.f, 0.f};
        if (row0 + rr < nrows)
            xv = *reinterpret_cast<const float4*>(&x[(long long)(row0 + rr) * H + cc]);
        *reinterpret_cast<float4*>(&Xs[rr][cc]) = xv;
    }

    // ---- phase A: 8-deep rotated-pipeline gather, wbf loads bypass L1 (sc0) ----
    int wv = tid >> 6;
    int lane = tid & 63;
    #pragma unroll
    for (int rr4 = 0; rr4 < 4; ++rr4) {
        int rr = wv * 4 + rr4;
        int d = row0 + rr;
        float ax = 0.f, ay = 0.f;
        if (d < nrows) {
            int i0 = __builtin_amdgcn_readfirstlane(off[d]);
            int i1 = __builtin_amdgcn_readfirstlane(end[d]);
            if (i1 > i0) {
                int2 e[8];
                // prologue: first chunk of csr entries (clamped, zero-weight pad)
                #pragma unroll
                for (int u = 0; u < 8; ++u) {
                    int jj = i0 + u;
                    int2 t = csr[jj < i1 ? jj : i0];
                    if (jj >= i1) t.y = 0;
                    e[u] = t;
                }
                for (int j = i0; j < i1; j += 8) {
                    // 1) issue 8 independent L1-bypass loads for current chunk
                    unsigned int uu[8];
                    float w[8];
                    #pragma unroll
                    for (int u = 0; u < 8; ++u) {
                        unsigned int voff = ((unsigned int)e[u].x * 64u + (unsigned int)lane) * 4u;
                        asm volatile("global_load_dword %0, %1, %2 sc0"
                                     : "=v"(uu[u]) : "v"(voff), "s"(wbf));
                        w[u] = __int_as_float(e[u].y);
                    }
                    // 2) prefetch next chunk's csr entries (hides under vm loads)
                    #pragma unroll
                    for (int u = 0; u < 8; ++u) {
                        int jj = j + 8 + u;
                        int2 t = csr[jj < i1 ? jj : i0];
                        if (jj >= i1) t.y = 0;
                        e[u] = t;
                    }
                    // 3) wait for the asm loads, then consume
                    asm volatile("s_waitcnt vmcnt(0)" ::: "memory");
                    __builtin_amdgcn_sched_barrier(0);
                    #pragma unroll
                    for (int u = 0; u < 8; ++u) {
                        ax += w[u] * __uint_as_float(uu[u] << 16);
                        ay += w[u] * __uint_as_float(uu[u] & 0xffff0000u);
                    }
                }
            }
        }
        *reinterpret_cast<float2*>(&As[rr][lane * 2]) = make_float2(ax, ay);
    }
    __syncthreads();

    // ---- phase B: t4 = agg + agg@Wc1 + x@W3 + b4 (scalar, proven lean) ----
    int c2 = (tid & 63) * 2;
    int rbase = (tid >> 6) * 4;
    float2 b4v = *reinterpret_cast<const float2*>(&b4[c2]);
    float acc[4][2];
    #pragma unroll
    for (int r = 0; r < 4; ++r) {
        acc[r][0] = As[rbase + r][c2]     + b4v.x;   // identity term of (I + W_cat1)
        acc[r][1] = As[rbase + r][c2 + 1] + b4v.y;
    }

    for (int k = 0; k < H; k += 4) {
        float2 w1[4], w3[4];
        #pragma unroll
        for (int kk = 0; kk < 4; ++kk) {
            w1[kk] = *reinterpret_cast<const float2*>(&Wc1[(k + kk) * H + c2]);
            w3[kk] = *reinterpret_cast<const float2*>(&W3[(k + kk) * H + c2]);
        }
        #pragma unroll
        for (int r = 0; r < 4; ++r) {
            float4 a  = *reinterpret_cast<const float4*>(&As[rbase + r][k]);
            float4 xv = *reinterpret_cast<const float4*>(&Xs[rbase + r][k]);
            acc[r][0] += a.x * w1[0].x + a.y * w1[1].x + a.z * w1[2].x + a.w * w1[3].x
                       + xv.x * w3[0].x + xv.y * w3[1].x + xv.z * w3[2].x + xv.w * w3[3].x;
            acc[r][1] += a.x * w1[0].y + a.y * w1[1].y + a.z * w1[2].y + a.w * w1[3].y
                       + xv.x * w3[0].y + xv.y * w3[1].y + xv.z * w3[2].y + xv.w * w3[3].y;
        }
    }

    // ---- relu, stash back to LDS ----
    __syncthreads();
    #pragma unroll
    for (int r = 0; r < 4; ++r) {
        As[rbase + r][c2]     = fmaxf(acc[r][0], 0.f);
        As[rbase + r][c2 + 1] = fmaxf(acc[r][1], 0.f);
    }
    __syncthreads();

    // ---- phase C: out = relu(t4) @ Wf + bf ----
    float2 bfv = *reinterpret_cast<const float2*>(&bf[c2]);
    float acc2[4][2];
    #pragma unroll
    for (int r = 0; r < 4; ++r) {
        acc2[r][0] = bfv.x;
        acc2[r][1] = bfv.y;
    }

    for (int k = 0; k < H; k += 4) {
        float2 wf[4];
        #pragma unroll
        for (int kk = 0; kk < 4; ++kk)
            wf[kk] = *reinterpret_cast<const float2*>(&Wf[(k + kk) * H + c2]);
        #pragma unroll
        for (int r = 0; r < 4; ++r) {
            float4 v = *reinterpret_cast<const float4*>(&As[rbase + r][k]);
            acc2[r][0] += v.x * wf[0].x + v.y * wf[1].x + v.z * wf[2].x + v.w * wf[3].x;
            acc2[r][1] += v.x * wf[0].y + v.y * wf[1].y + v.z * wf[2].y + v.w * wf[3].y;
        }
    }

    #pragma unroll
    for (int r = 0; r < 4; ++r) {
        int row = row0 + rbase + r;
        if (row < nrows) {
            float2 o{acc2[r][0], acc2[r][1]};
            *reinterpret_cast<float2*>(&out[(long long)row * H + c2]) = o;
        }
    }
}

extern "C" void kernel_launch(void* const* d_in, const int* in_sizes, int n_in,
                              void* d_out, int out_size, void* d_ws, size_t ws_size,
                              hipStream_t stream) {
    const float* x       = (const float*)d_in[0];
    const int*   ei      = (const int*)d_in[1];
    const float* ew      = (const float*)d_in[2];
    const float* W_edge  = (const float*)d_in[3];
    const float* b_edge  = (const float*)d_in[4];
    const float* W_node  = (const float*)d_in[5];
    const float* b_node  = (const float*)d_in[6];
    const float* W_cat1  = (const float*)d_in[7];
    const float* b_cat1  = (const float*)d_in[8];
    const float* W_cat2  = (const float*)d_in[9];
    const float* b_cat2  = (const float*)d_in[10];
    const float* W_final = (const float*)d_in[11];
    const float* b_final = (const float*)d_in[12];
    float* out = (float*)d_out;

    // workspace layout
    int*  deg  = (int*)d_ws;                         // NN
    int*  off  = deg + NN;                           // NN
    int*  cur  = off + NN;                           // NN
    int*  sums = cur + NN;                           // 512
    int2* csr  = (int2*)(sums + 512);                // NE   (8B aligned: offset 1202048)
    unsigned int* wbf = (unsigned int*)(csr + NE);   // NN*64 packed bf16 pairs (25.6 MB)
    float* W3  = (float*)(wbf + (size_t)NN * 64);    // H*H
    float* b4  = W3 + H * H;                         // H

    // 1. CSR build
    zero_int<<<(NN + 255) / 256, 256, 0, stream>>>(deg, NN);
    hist_kernel<<<(NE + 255) / 256, 256, 0, stream>>>(ei, deg);
    scan_block<<<NB_SCAN, SCAN_CHUNK, 0, stream>>>(deg, off, sums, NN);
    scan_sums<<<1, 256, 0, stream>>>(sums, NB_SCAN);
    scan_add<<<(NN + 255) / 256, 256, 0, stream>>>(off, sums, cur, NN);
    fill_kernel<<<(NE + 255) / 256, 256, 0, stream>>>(ei, ew, cur, csr);

    // 2. W_edge -> bf16, merged precompute (W3 + b4)
    conv_bf16<<<(NN * H / 2 + 255) / 256, 256, 0, stream>>>(W_edge, wbf, NN * H / 2);
    precompute_all<<<H + 1, H, 0, stream>>>(W_node, W_cat2, b_edge, W_cat1,
                                            b_node, b_cat1, b_cat2, W3, b4);

    // 3. fully fused gather + affine + relu + final linear -> d_out
    gather_fused<<<(NN + 15) / 16, 256, 0, stream>>>(off, cur, csr, wbf, x,
                                                     W_cat1, W3, b4,
                                                     W_final, b_final, out, NN);
}